// Round 1
// baseline (59.676 us; speedup 1.0000x reference)
//
#include <hip/hip_runtime.h>
#include <hip/hip_bf16.h>

#define NB 16384
#define NF 39
#define NK 64
#define WROW 12   // padded bf16 row stride (10 used + 2 pad) -> 24B rows, 8B aligned

__device__ __forceinline__ float bf_lo(unsigned u) { return __uint_as_float(u << 16); }
__device__ __forceinline__ float bf_hi(unsigned u) { return __uint_as_float(u & 0xffff0000u); }

__device__ __forceinline__ unsigned short f2bf(float f) {
    unsigned u = __float_as_uint(f);
    unsigned r = (u + 0x7fffu + ((u >> 16) & 1u)) >> 16;   // RNE, no NaN handling needed
    return (unsigned short)r;
}

__global__ __launch_bounds__(512, 4)
void deepfm_kernel(const int* __restrict__ feature,
                   const float* __restrict__ v_table,
                   const float* __restrict__ w_table,
                   const float* __restrict__ w0s,
                   const float* __restrict__ W0,
                   const float* __restrict__ b0,
                   const float* __restrict__ W1,
                   const float* __restrict__ b1,
                   const float* __restrict__ W2,
                   const float* __restrict__ b2,
                   const float* __restrict__ W3,
                   const float* __restrict__ b3,
                   float* __restrict__ out)
{
    __shared__ unsigned short w0_lds[NF * NK * WROW];   // 2496*12*2 = 59904 B

    // ---- stage W0 fp32 [2496][10] -> LDS bf16 [2496][12] ----
    for (int i = threadIdx.x; i < NF * NK; i += 512) {
        #pragma unroll
        for (int j = 0; j < 10; ++j)
            w0_lds[i * WROW + j] = f2bf(W0[i * 10 + j]);
        w0_lds[i * WROW + 10] = 0;
        w0_lds[i * WROW + 11] = 0;
    }
    __syncthreads();

    const int lane = threadIdx.x & 63;
    const int wave = threadIdx.x >> 6;            // 0..7
    const int s0   = blockIdx.x * 32 + wave * 4;  // 4 consecutive samples per wave

    float h0p[4][10];
    float sv[4], sq[4], lin[4];
    #pragma unroll
    for (int s = 0; s < 4; ++s) {
        sv[s] = 0.f; sq[s] = 0.f; lin[s] = 0.f;
        #pragma unroll
        for (int j = 0; j < 10; ++j) h0p[s][j] = 0.f;
    }

    const unsigned* wlds = (const unsigned*)w0_lds;   // row i starts at uint i*6

    #pragma unroll 2
    for (int f = 0; f < NF; ++f) {
        int   idx[4];
        float v[4];
        #pragma unroll
        for (int s = 0; s < 4; ++s) {
            idx[s] = feature[(s0 + s) * NF + f];                 // wave-uniform -> scalar load
            v[s]   = v_table[(size_t)idx[s] * NK + lane];        // coalesced 256B gather
            lin[s] += w_table[idx[s]];                           // uniform broadcast, L2-hit
        }
        const unsigned* wr = wlds + (f * NK + lane) * (WROW / 2);
        uint2    wa = *(const uint2*)(wr);
        uint2    wb = *(const uint2*)(wr + 2);
        unsigned wc = wr[4];
        float wj[10] = { bf_lo(wa.x), bf_hi(wa.x), bf_lo(wa.y), bf_hi(wa.y),
                         bf_lo(wb.x), bf_hi(wb.x), bf_lo(wb.y), bf_hi(wb.y),
                         bf_lo(wc),   bf_hi(wc) };
        #pragma unroll
        for (int s = 0; s < 4; ++s) {
            sv[s] += v[s];
            sq[s] = fmaf(v[s], v[s], sq[s]);
            #pragma unroll
            for (int j = 0; j < 10; ++j)
                h0p[s][j] = fmaf(v[s], wj[j], h0p[s][j]);
        }
    }

    const float w0v = w0s[0];

    #pragma unroll
    for (int s = 0; s < 4; ++s) {
        float t = fmaf(sv[s], sv[s], -sq[s]);   // s_k^2 - sum_f v^2 (per lane k)
        #pragma unroll
        for (int m = 1; m < 64; m <<= 1) {
            t += __shfl_xor(t, m, 64);
            #pragma unroll
            for (int j = 0; j < 10; ++j)
                h0p[s][j] += __shfl_xor(h0p[s][j], m, 64);
        }
        // tiny MLP tail (computed redundantly on all lanes; values are wave-uniform now)
        float h0v[10];
        #pragma unroll
        for (int j = 0; j < 10; ++j) h0v[j] = fmaxf(h0p[s][j] + b0[j], 0.f);
        float h1[5];
        #pragma unroll
        for (int p = 0; p < 5; ++p) {
            float a = b1[p];
            #pragma unroll
            for (int j = 0; j < 10; ++j) a = fmaf(h0v[j], W1[j * 5 + p], a);
            h1[p] = fmaxf(a, 0.f);
        }
        float h2[3];
        #pragma unroll
        for (int q = 0; q < 3; ++q) {
            float a = b2[q];
            #pragma unroll
            for (int p = 0; p < 5; ++p) a = fmaf(h1[p], W2[p * 3 + q], a);
            h2[q] = fmaxf(a, 0.f);
        }
        float dnn = b3[0];
        #pragma unroll
        for (int q = 0; q < 3; ++q) dnn = fmaf(h2[q], W3[q], dnn);

        if (lane == 0) out[s0 + s] = 0.5f * t + lin[s] + w0v + dnn;
    }
}

extern "C" void kernel_launch(void* const* d_in, const int* in_sizes, int n_in,
                              void* d_out, int out_size, void* d_ws, size_t ws_size,
                              hipStream_t stream) {
    const int*   feature = (const int*)  d_in[0];
    const float* v_table = (const float*)d_in[1];
    const float* w_table = (const float*)d_in[2];
    const float* w0s     = (const float*)d_in[3];
    const float* W0      = (const float*)d_in[4];
    const float* b0      = (const float*)d_in[5];
    const float* W1      = (const float*)d_in[6];
    const float* b1      = (const float*)d_in[7];
    const float* W2      = (const float*)d_in[8];
    const float* b2      = (const float*)d_in[9];
    const float* W3      = (const float*)d_in[10];
    const float* b3      = (const float*)d_in[11];

    deepfm_kernel<<<dim3(512), dim3(512), 0, stream>>>(
        feature, v_table, w_table, w0s, W0, b0, W1, b1, W2, b2, W3, b3,
        (float*)d_out);
}